// Round 1
// baseline (684.288 us; speedup 1.0000x reference)
//
#include <hip/hip_runtime.h>

// ---------------------------------------------------------------------------
// 3-layer GCN (PyG gcn_norm semantics) on MI355X.
// Pipeline per call (all on `stream`):
//   0. detect edge_index storage (int32 vs int64) deterministically on-device
//   1. degree count (atomics) -> dis = rsqrt(deg+1)
//   2. exclusive scan -> CSR offsets ; fill CSR (src row + norm weight)
//   3. H0 = x @ W1            (fp32 tiled GEMM, K-split x4 + reduce)
//   4. H1 = relu(Agg(H0)+b1)  (CSR gather, F=64)
//   5. H2a = H1 @ W2 ; H2 = relu(Agg(H2a)+b2)   (F=32)
//   6. H3a = H2 @ W3 ; out = softmax(Agg(H3a)+b3) (F=16, fused)
// ---------------------------------------------------------------------------

// --- edge_index layout probe: if stored as int64 (values < 2^31), every odd
// 32-bit word is 0. If int32, odd words are random node ids (P(all 0) ~ 0).
__global__ void detect_i64_k(const int* __restrict__ ei, int* __restrict__ flag) {
    if (blockIdx.x == 0 && threadIdx.x == 0) {
        int f = 1;
        for (int i = 0; i < 256; ++i) {
            if (ei[2 * i + 1] != 0) { f = 0; break; }
        }
        *flag = f;
    }
}

__device__ __forceinline__ int edge_val(const int* __restrict__ ei, long long idx, int f64) {
    return f64 ? ei[2 * idx] : ei[(int)idx];
}

__global__ void count_deg_k(const int* __restrict__ ei, int E, const int* __restrict__ flag,
                            int* __restrict__ cnt) {
    int e = blockIdx.x * blockDim.x + threadIdx.x;
    if (e >= E) return;
    int f = *flag;
    int c = edge_val(ei, (long long)E + e, f);
    atomicAdd(&cnt[c], 1);
}

__global__ void dis_k(const int* __restrict__ cnt, float* __restrict__ dis, int n) {
    int i = blockIdx.x * blockDim.x + threadIdx.x;
    if (i < n) dis[i] = rsqrtf((float)(cnt[i] + 1));  // +1: self loop
}

// single-block exclusive scan over n (= 16384) counts; 1024 threads x 16 each
__global__ void scan_k(const int* __restrict__ cnt, int* __restrict__ offs, int n) {
    __shared__ int sums[1024];
    const int t = threadIdx.x;
    const int base = t * 16;
    int loc[16];
    int s = 0;
#pragma unroll
    for (int i = 0; i < 16; ++i) {
        loc[i] = s;
        int idx = base + i;
        s += (idx < n) ? cnt[idx] : 0;
    }
    sums[t] = s;
    __syncthreads();
    for (int o = 1; o < 1024; o <<= 1) {
        int v = (t >= o) ? sums[t - o] : 0;
        __syncthreads();
        sums[t] += v;
        __syncthreads();
    }
    int tbase = (t == 0) ? 0 : sums[t - 1];
#pragma unroll
    for (int i = 0; i < 16; ++i) {
        int idx = base + i;
        if (idx < n) offs[idx] = tbase + loc[i];
    }
    if (t == 1023) offs[n] = sums[1023];
}

__global__ void fill_csr_k(const int* __restrict__ ei, int E, const int* __restrict__ flag,
                           const int* __restrict__ offs, int* __restrict__ cursor,
                           const float* __restrict__ dis, int* __restrict__ src,
                           float* __restrict__ w) {
    int e = blockIdx.x * blockDim.x + threadIdx.x;
    if (e >= E) return;
    int f = *flag;
    int r = edge_val(ei, (long long)e, f);
    int c = edge_val(ei, (long long)E + e, f);
    int pos = offs[c] + atomicAdd(&cursor[c], 1);
    src[pos] = r;
    w[pos] = dis[r] * dis[c];
}

// --- GEMM1: [n x K] @ [K x 64], fp32, 64x64 tile, BK=32, 256 thr, 4x4/thread,
//     K split into 4 chunks (blockIdx.y) writing partials P[kz] for occupancy.
__global__ __launch_bounds__(256) void gemm1_k(const float* __restrict__ A,
                                               const float* __restrict__ B,
                                               float* __restrict__ P, int n, int K,
                                               int kchunk) {
    __shared__ float As[64][36];  // pad 36: 16B-aligned f4 stores, low-conflict col reads
    __shared__ float Bs[32][64];
    const int tid = threadIdx.x;
    const int bm = blockIdx.x * 64;
    const int k0 = blockIdx.y * kchunk;
    const int k1 = k0 + kchunk;
    const int tx = tid & 15, ty = tid >> 4;
    float acc[4][4] = {};

    for (int kb = k0; kb < k1; kb += 32) {
#pragma unroll
        for (int i = 0; i < 2; ++i) {
            int v = tid + i * 256;
            int r = v >> 3, ca = (v & 7) * 4;               // A: 8 float4 per row
            float4 fa = *(const float4*)(A + (size_t)(bm + r) * K + kb + ca);
            *(float4*)&As[r][ca] = fa;
            int rb = v >> 4, cb = (v & 15) * 4;             // B: 16 float4 per row
            float4 fb = *(const float4*)(B + (size_t)(kb + rb) * 64 + cb);
            *(float4*)&Bs[rb][cb] = fb;
        }
        __syncthreads();
#pragma unroll
        for (int k = 0; k < 32; ++k) {
            float4 b = *(const float4*)&Bs[k][tx * 4];
            float a0 = As[ty * 4 + 0][k];
            float a1 = As[ty * 4 + 1][k];
            float a2 = As[ty * 4 + 2][k];
            float a3 = As[ty * 4 + 3][k];
            acc[0][0] = fmaf(a0, b.x, acc[0][0]);
            acc[0][1] = fmaf(a0, b.y, acc[0][1]);
            acc[0][2] = fmaf(a0, b.z, acc[0][2]);
            acc[0][3] = fmaf(a0, b.w, acc[0][3]);
            acc[1][0] = fmaf(a1, b.x, acc[1][0]);
            acc[1][1] = fmaf(a1, b.y, acc[1][1]);
            acc[1][2] = fmaf(a1, b.z, acc[1][2]);
            acc[1][3] = fmaf(a1, b.w, acc[1][3]);
            acc[2][0] = fmaf(a2, b.x, acc[2][0]);
            acc[2][1] = fmaf(a2, b.y, acc[2][1]);
            acc[2][2] = fmaf(a2, b.z, acc[2][2]);
            acc[2][3] = fmaf(a2, b.w, acc[2][3]);
            acc[3][0] = fmaf(a3, b.x, acc[3][0]);
            acc[3][1] = fmaf(a3, b.y, acc[3][1]);
            acc[3][2] = fmaf(a3, b.z, acc[3][2]);
            acc[3][3] = fmaf(a3, b.w, acc[3][3]);
        }
        __syncthreads();
    }
    float* out = P + (size_t)blockIdx.y * n * 64;
#pragma unroll
    for (int i = 0; i < 4; ++i) {
        float4 v = make_float4(acc[i][0], acc[i][1], acc[i][2], acc[i][3]);
        *(float4*)(out + (size_t)(bm + ty * 4 + i) * 64 + tx * 4) = v;
    }
}

__global__ void reduce4_k(float4* __restrict__ p, size_t q) {
    size_t i = (size_t)blockIdx.x * blockDim.x + threadIdx.x;
    if (i >= q) return;
    float4 a = p[i], b = p[i + q], c = p[i + 2 * q], d = p[i + 3 * q];
    a.x += b.x + c.x + d.x;
    a.y += b.y + c.y + d.y;
    a.z += b.z + c.z + d.z;
    a.w += b.w + c.w + d.w;
    p[i] = a;
}

// --- propagate: out[i,c] = sum_{e in CSR[i]} w_e*h[src_e,c] + dis[i]^2*h[i,c] + b[c]
template <int F, bool RELU>
__global__ void prop_k(const float* __restrict__ h, const int* __restrict__ offs,
                       const int* __restrict__ src, const float* __restrict__ w,
                       const float* __restrict__ dis, const float* __restrict__ b,
                       float* __restrict__ out, int n) {
    int t = blockIdx.x * blockDim.x + threadIdx.x;
    int node = t / F, c = t % F;
    if (node >= n) return;
    float acc = 0.f;
    int p0 = offs[node], p1 = offs[node + 1];
    for (int p = p0; p < p1; ++p) {
        acc = fmaf(w[p], h[(size_t)src[p] * F + c], acc);
    }
    float d = dis[node];
    acc = fmaf(d * d, h[(size_t)node * F + c], acc) + b[c];
    if (RELU) acc = fmaxf(acc, 0.f);
    out[t] = acc;
}

// --- small dense layer: out[n x FO] = h[n x K] @ W[K x FO]
template <int K, int FO>
__global__ void gemm_small_k(const float* __restrict__ h, const float* __restrict__ W,
                             float* __restrict__ out, int n) {
    __shared__ float Ws[K * FO];
    for (int i = threadIdx.x; i < K * FO; i += blockDim.x) Ws[i] = W[i];
    __syncthreads();
    int t = blockIdx.x * blockDim.x + threadIdx.x;
    int node = t / FO, c = t % FO;
    if (node >= n) return;
    const float* hr = h + (size_t)node * K;
    float acc = 0.f;
#pragma unroll
    for (int k = 0; k < K; ++k) acc = fmaf(hr[k], Ws[k * FO + c], acc);
    out[t] = acc;
}

// --- final propagate (F=16) + bias + softmax over 16 lanes, fused
__global__ void prop_softmax_k(const float* __restrict__ h, const int* __restrict__ offs,
                               const int* __restrict__ src, const float* __restrict__ w,
                               const float* __restrict__ dis, const float* __restrict__ b,
                               float* __restrict__ out, int n) {
    int t = blockIdx.x * blockDim.x + threadIdx.x;
    int node = t >> 4, c = t & 15;
    if (node >= n) return;
    float acc = 0.f;
    int p0 = offs[node], p1 = offs[node + 1];
    for (int p = p0; p < p1; ++p) {
        acc = fmaf(w[p], h[(size_t)src[p] * 16 + c], acc);
    }
    float d = dis[node];
    acc = fmaf(d * d, h[(size_t)node * 16 + c], acc) + b[c];
    float m = acc;
#pragma unroll
    for (int o = 8; o; o >>= 1) m = fmaxf(m, __shfl_xor(m, o, 16));
    float ex = __expf(acc - m);
    float s = ex;
#pragma unroll
    for (int o = 8; o; o >>= 1) s += __shfl_xor(s, o, 16);
    out[t] = ex / s;
}

extern "C" void kernel_launch(void* const* d_in, const int* in_sizes, int n_in,
                              void* d_out, int out_size, void* d_ws, size_t ws_size,
                              hipStream_t stream) {
    const float* x  = (const float*)d_in[0];
    const int*   ei = (const int*)d_in[1];
    const float* W1 = (const float*)d_in[2];
    const float* b1 = (const float*)d_in[3];
    const float* W2 = (const float*)d_in[4];
    const float* b2 = (const float*)d_in[5];
    const float* W3 = (const float*)d_in[6];
    const float* b3 = (const float*)d_in[7];
    float* out = (float*)d_out;

    const int n = in_sizes[2] / 64;   // W1 is [n x 64]
    const int K = in_sizes[0] / n;    // x is [n x K] (= n)
    const int E = in_sizes[1] / 2;    // edge_index is [2 x E]

    char* ws = (char*)d_ws;
    size_t off = 0;
    auto alloc = [&](size_t bytes) {
        char* p = ws + off;
        off = (off + bytes + 255) & ~(size_t)255;
        return p;
    };
    int*   flag   = (int*)  alloc(4);
    int*   cnt    = (int*)  alloc((size_t)n * 4);
    int*   cursor = (int*)  alloc((size_t)n * 4);
    int*   offs   = (int*)  alloc((size_t)(n + 1) * 4);
    float* dis    = (float*)alloc((size_t)n * 4);
    int*   csrs   = (int*)  alloc((size_t)E * 4);
    float* csrw   = (float*)alloc((size_t)E * 4);
    float* P      = (float*)alloc((size_t)4 * n * 64 * 4);  // GEMM1 partials; P = H0 after reduce
    float* H1     = (float*)alloc((size_t)n * 64 * 4);
    float* H2a    = (float*)alloc((size_t)n * 32 * 4);
    float* H2     = (float*)alloc((size_t)n * 32 * 4);
    float* H3a    = (float*)alloc((size_t)n * 16 * 4);
    (void)ws_size; (void)n_in; (void)out_size;

    hipMemsetAsync(cnt, 0, (size_t)n * 4, stream);
    hipMemsetAsync(cursor, 0, (size_t)n * 4, stream);

    detect_i64_k<<<1, 64, 0, stream>>>(ei, flag);
    count_deg_k<<<(E + 255) / 256, 256, 0, stream>>>(ei, E, flag, cnt);
    dis_k<<<(n + 255) / 256, 256, 0, stream>>>(cnt, dis, n);
    scan_k<<<1, 1024, 0, stream>>>(cnt, offs, n);
    fill_csr_k<<<(E + 255) / 256, 256, 0, stream>>>(ei, E, flag, offs, cursor, dis, csrs, csrw);

    dim3 g1(n / 64, 4);
    gemm1_k<<<g1, 256, 0, stream>>>(x, W1, P, n, K, K / 4);
    size_t q = (size_t)n * 64 / 4;
    reduce4_k<<<(int)((q + 255) / 256), 256, 0, stream>>>((float4*)P, q);

    prop_k<64, true><<<(n * 64 + 255) / 256, 256, 0, stream>>>(P, offs, csrs, csrw, dis, b1, H1, n);
    gemm_small_k<64, 32><<<(n * 32 + 255) / 256, 256, 0, stream>>>(H1, W2, H2a, n);
    prop_k<32, true><<<(n * 32 + 255) / 256, 256, 0, stream>>>(H2a, offs, csrs, csrw, dis, b2, H2, n);
    gemm_small_k<32, 16><<<(n * 16 + 255) / 256, 256, 0, stream>>>(H2, W3, H3a, n);
    prop_softmax_k<<<(n * 16 + 255) / 256, 256, 0, stream>>>(H3a, offs, csrs, csrw, dis, b3, out, n);
}

// Round 2
// 435.837 us; speedup vs baseline: 1.5701x; 1.5701x over previous
//
#include <hip/hip_runtime.h>

// ---------------------------------------------------------------------------
// 3-layer GCN (PyG gcn_norm semantics) on MI355X.
//   0. detect edge_index storage (int32 vs int64) on-device
//   1. degree count -> dis = rsqrt(deg+1) ; scan -> CSR offsets ; fill CSR
//   2. W1 -> split bf16 hi/lo + transpose (Bt[2][64][K], one-time ~4MB)
//   3. H0 = x @ W1 via split-bf16 MFMA (xh*Wh + xl*Wh + xh*Wl), K-split x4
//   4. H1 = relu(Agg(H0)+b1) ; H2 = relu(Agg(H1@W2)+b2)
//   5. out = softmax(Agg(H2@W3)+b3)
// ---------------------------------------------------------------------------

typedef __attribute__((ext_vector_type(8))) short bf16x8;
typedef __attribute__((ext_vector_type(4))) float f32x4;

__device__ __forceinline__ unsigned short f2bf_rne(float f) {
    unsigned u = __float_as_uint(f);
    unsigned r = (u + 0x7FFFu + ((u >> 16) & 1u)) >> 16;
    return (unsigned short)r;
}

// --- edge_index layout probe: int64 values < 2^31 -> every odd 32b word is 0.
__global__ void detect_i64_k(const int* __restrict__ ei, int* __restrict__ flag) {
    if (blockIdx.x == 0 && threadIdx.x == 0) {
        int f = 1;
        for (int i = 0; i < 256; ++i) {
            if (ei[2 * i + 1] != 0) { f = 0; break; }
        }
        *flag = f;
    }
}

__device__ __forceinline__ int edge_val(const int* __restrict__ ei, long long idx, int f64) {
    return f64 ? ei[2 * idx] : ei[(int)idx];
}

__global__ void count_deg_k(const int* __restrict__ ei, int E, const int* __restrict__ flag,
                            int* __restrict__ cnt) {
    int e = blockIdx.x * blockDim.x + threadIdx.x;
    if (e >= E) return;
    int f = *flag;
    int c = edge_val(ei, (long long)E + e, f);
    atomicAdd(&cnt[c], 1);
}

__global__ void dis_k(const int* __restrict__ cnt, float* __restrict__ dis, int n) {
    int i = blockIdx.x * blockDim.x + threadIdx.x;
    if (i < n) dis[i] = rsqrtf((float)(cnt[i] + 1));
}

__global__ void scan_k(const int* __restrict__ cnt, int* __restrict__ offs, int n) {
    __shared__ int sums[1024];
    const int t = threadIdx.x;
    const int base = t * 16;
    int loc[16];
    int s = 0;
#pragma unroll
    for (int i = 0; i < 16; ++i) {
        loc[i] = s;
        int idx = base + i;
        s += (idx < n) ? cnt[idx] : 0;
    }
    sums[t] = s;
    __syncthreads();
    for (int o = 1; o < 1024; o <<= 1) {
        int v = (t >= o) ? sums[t - o] : 0;
        __syncthreads();
        sums[t] += v;
        __syncthreads();
    }
    int tbase = (t == 0) ? 0 : sums[t - 1];
#pragma unroll
    for (int i = 0; i < 16; ++i) {
        int idx = base + i;
        if (idx < n) offs[idx] = tbase + loc[i];
    }
    if (t == 1023) offs[n] = sums[1023];
}

__global__ void fill_csr_k(const int* __restrict__ ei, int E, const int* __restrict__ flag,
                           const int* __restrict__ offs, int* __restrict__ cursor,
                           const float* __restrict__ dis, int* __restrict__ src,
                           float* __restrict__ w) {
    int e = blockIdx.x * blockDim.x + threadIdx.x;
    if (e >= E) return;
    int f = *flag;
    int r = edge_val(ei, (long long)e, f);
    int c = edge_val(ei, (long long)E + e, f);
    int pos = offs[c] + atomicAdd(&cursor[c], 1);
    src[pos] = r;
    w[pos] = dis[r] * dis[c];
}

// --- W1 [K][64] fp32 -> Bt[2][64][K] bf16 (hi, lo), transposed. One-time.
__global__ void prep_w1_k(const float* __restrict__ W1, unsigned short* __restrict__ Bt,
                          int K) {
    int g = blockIdx.x * blockDim.x + threadIdx.x;
    if (g >= K * 64) return;
    int nn = g & 63, k = g >> 6;
    float f = W1[(size_t)k * 64 + nn];
    unsigned short hi = f2bf_rne(f);
    float hf = __uint_as_float((unsigned)hi << 16);
    unsigned short lo = f2bf_rne(f - hf);
    Bt[(size_t)nn * K + k] = hi;
    Bt[(size_t)64 * K + (size_t)nn * K + k] = lo;
}

// --- GEMM1: [n x K] fp32 @ Bt -> P[kz][n][64], split-bf16 MFMA.
// BM=128, BN=64, BK=32, 256 thr = 4 waves (2m x 2n), wave tile 64x32.
__global__ __launch_bounds__(256) void gemm1_mfma_k(
    const float* __restrict__ A, const unsigned short* __restrict__ Bt,
    float* __restrict__ P, int n, int K, int kchunk) {
    __shared__ unsigned short As[2][128][40];  // [hi/lo][row][k], pad 40 -> uniform banks
    const int tid = threadIdx.x;
    const int lane = tid & 63;
    const int wid = tid >> 6;
    const int wm = wid >> 1, wn = wid & 1;
    const int lrow = lane & 15, lkh = lane >> 4;
    const int bm = blockIdx.x * 128;
    const int k0 = blockIdx.y * kchunk;
    const int iters = kchunk / 32;

    const unsigned short* Bh = Bt;
    const unsigned short* Bl = Bt + (size_t)64 * K;

    f32x4 acc[4][2] = {};

    float4 st[4];
    auto loadA = [&](int kt) {
#pragma unroll
        for (int i = 0; i < 4; ++i) {
            int v = tid + i * 256;
            int r = v >> 3, c = (v & 7) * 4;
            st[i] = *(const float4*)(A + (size_t)(bm + r) * K + k0 + kt * 32 + c);
        }
    };

    loadA(0);
    for (int kt = 0; kt < iters; ++kt) {
        // B fragments straight from global (L2-hot 4MB, reused by all blocks)
        bf16x8 bh[2], bl[2];
#pragma unroll
        for (int nf = 0; nf < 2; ++nf) {
            int brow = wn * 32 + nf * 16 + lrow;
            size_t bo = (size_t)brow * K + k0 + kt * 32 + lkh * 8;
            bh[nf] = *(const bf16x8*)(Bh + bo);
            bl[nf] = *(const bf16x8*)(Bl + bo);
        }
        // convert staged A regs -> hi/lo bf16 -> LDS
#pragma unroll
        for (int i = 0; i < 4; ++i) {
            int v = tid + i * 256;
            int r = v >> 3, c = (v & 7) * 4;
            float fs[4] = {st[i].x, st[i].y, st[i].z, st[i].w};
            ushort4 uh, ul;
            unsigned short* ph = &uh.x;
            unsigned short* pl = &ul.x;
#pragma unroll
            for (int j = 0; j < 4; ++j) {
                unsigned short hi = f2bf_rne(fs[j]);
                float hf = __uint_as_float((unsigned)hi << 16);
                ph[j] = hi;
                pl[j] = f2bf_rne(fs[j] - hf);
            }
            *(ushort4*)&As[0][r][c] = uh;
            *(ushort4*)&As[1][r][c] = ul;
        }
        __syncthreads();
        if (kt + 1 < iters) loadA(kt + 1);  // prefetch under MFMA
        bf16x8 ah[4], al[4];
#pragma unroll
        for (int mf = 0; mf < 4; ++mf) {
            int row = wm * 64 + mf * 16 + lrow;
            ah[mf] = *(const bf16x8*)&As[0][row][lkh * 8];
            al[mf] = *(const bf16x8*)&As[1][row][lkh * 8];
        }
#pragma unroll
        for (int mf = 0; mf < 4; ++mf)
#pragma unroll
            for (int nf = 0; nf < 2; ++nf) {
                acc[mf][nf] = __builtin_amdgcn_mfma_f32_16x16x32_bf16(ah[mf], bh[nf], acc[mf][nf], 0, 0, 0);
                acc[mf][nf] = __builtin_amdgcn_mfma_f32_16x16x32_bf16(al[mf], bh[nf], acc[mf][nf], 0, 0, 0);
                acc[mf][nf] = __builtin_amdgcn_mfma_f32_16x16x32_bf16(ah[mf], bl[nf], acc[mf][nf], 0, 0, 0);
            }
        __syncthreads();
    }
    // C/D layout: col = lane&15, row = (lane>>4)*4 + reg
    float* out = P + (size_t)blockIdx.y * n * 64;
#pragma unroll
    for (int mf = 0; mf < 4; ++mf)
#pragma unroll
        for (int nf = 0; nf < 2; ++nf)
#pragma unroll
            for (int j = 0; j < 4; ++j) {
                int row = bm + wm * 64 + mf * 16 + lkh * 4 + j;
                int col = wn * 32 + nf * 16 + lrow;
                out[(size_t)row * 64 + col] = acc[mf][nf][j];
            }
}

__global__ void reduce4_k(float4* __restrict__ p, size_t q) {
    size_t i = (size_t)blockIdx.x * blockDim.x + threadIdx.x;
    if (i >= q) return;
    float4 a = p[i], b = p[i + q], c = p[i + 2 * q], d = p[i + 3 * q];
    a.x += b.x + c.x + d.x;
    a.y += b.y + c.y + d.y;
    a.z += b.z + c.z + d.z;
    a.w += b.w + c.w + d.w;
    p[i] = a;
}

// --- propagate: out[i,c] = sum_e w_e*h[src_e,c] + dis[i]^2*h[i,c] + b[c]
template <int F, bool RELU>
__global__ void prop_k(const float* __restrict__ h, const int* __restrict__ offs,
                       const int* __restrict__ src, const float* __restrict__ w,
                       const float* __restrict__ dis, const float* __restrict__ b,
                       float* __restrict__ out, int n) {
    int t = blockIdx.x * blockDim.x + threadIdx.x;
    int node = t / F, c = t % F;
    if (node >= n) return;
    float acc = 0.f;
    int p0 = offs[node], p1 = offs[node + 1];
    for (int p = p0; p < p1; ++p) {
        acc = fmaf(w[p], h[(size_t)src[p] * F + c], acc);
    }
    float d = dis[node];
    acc = fmaf(d * d, h[(size_t)node * F + c], acc) + b[c];
    if (RELU) acc = fmaxf(acc, 0.f);
    out[t] = acc;
}

template <int K, int FO>
__global__ void gemm_small_k(const float* __restrict__ h, const float* __restrict__ W,
                             float* __restrict__ out, int n) {
    __shared__ float Ws[K * FO];
    for (int i = threadIdx.x; i < K * FO; i += blockDim.x) Ws[i] = W[i];
    __syncthreads();
    int t = blockIdx.x * blockDim.x + threadIdx.x;
    int node = t / FO, c = t % FO;
    if (node >= n) return;
    const float* hr = h + (size_t)node * K;
    float acc = 0.f;
#pragma unroll
    for (int k = 0; k < K; ++k) acc = fmaf(hr[k], Ws[k * FO + c], acc);
    out[t] = acc;
}

__global__ void prop_softmax_k(const float* __restrict__ h, const int* __restrict__ offs,
                               const int* __restrict__ src, const float* __restrict__ w,
                               const float* __restrict__ dis, const float* __restrict__ b,
                               float* __restrict__ out, int n) {
    int t = blockIdx.x * blockDim.x + threadIdx.x;
    int node = t >> 4, c = t & 15;
    if (node >= n) return;
    float acc = 0.f;
    int p0 = offs[node], p1 = offs[node + 1];
    for (int p = p0; p < p1; ++p) {
        acc = fmaf(w[p], h[(size_t)src[p] * 16 + c], acc);
    }
    float d = dis[node];
    acc = fmaf(d * d, h[(size_t)node * 16 + c], acc) + b[c];
    float m = acc;
#pragma unroll
    for (int o = 8; o; o >>= 1) m = fmaxf(m, __shfl_xor(m, o, 16));
    float ex = __expf(acc - m);
    float s = ex;
#pragma unroll
    for (int o = 8; o; o >>= 1) s += __shfl_xor(s, o, 16);
    out[t] = ex / s;
}

extern "C" void kernel_launch(void* const* d_in, const int* in_sizes, int n_in,
                              void* d_out, int out_size, void* d_ws, size_t ws_size,
                              hipStream_t stream) {
    const float* x  = (const float*)d_in[0];
    const int*   ei = (const int*)d_in[1];
    const float* W1 = (const float*)d_in[2];
    const float* b1 = (const float*)d_in[3];
    const float* W2 = (const float*)d_in[4];
    const float* b2 = (const float*)d_in[5];
    const float* W3 = (const float*)d_in[6];
    const float* b3 = (const float*)d_in[7];
    float* out = (float*)d_out;

    const int n = in_sizes[2] / 64;
    const int K = in_sizes[0] / n;
    const int E = in_sizes[1] / 2;

    char* ws = (char*)d_ws;
    size_t off = 0;
    auto alloc = [&](size_t bytes) {
        char* p = ws + off;
        off = (off + bytes + 255) & ~(size_t)255;
        return p;
    };
    int*   flag   = (int*)  alloc(4);
    int*   cnt    = (int*)  alloc((size_t)n * 4);
    int*   cursor = (int*)  alloc((size_t)n * 4);
    int*   offs   = (int*)  alloc((size_t)(n + 1) * 4);
    float* dis    = (float*)alloc((size_t)n * 4);
    int*   csrs   = (int*)  alloc((size_t)E * 4);
    float* csrw   = (float*)alloc((size_t)E * 4);
    unsigned short* Btw = (unsigned short*)alloc((size_t)2 * 64 * K * 2);
    float* P      = (float*)alloc((size_t)4 * n * 64 * 4);  // partials; P = H0 after reduce
    float* H1     = (float*)alloc((size_t)n * 64 * 4);
    float* H2a    = (float*)alloc((size_t)n * 32 * 4);
    float* H2     = (float*)alloc((size_t)n * 32 * 4);
    float* H3a    = (float*)alloc((size_t)n * 16 * 4);
    (void)ws_size; (void)n_in; (void)out_size;

    hipMemsetAsync(cnt, 0, (size_t)n * 4, stream);
    hipMemsetAsync(cursor, 0, (size_t)n * 4, stream);

    detect_i64_k<<<1, 64, 0, stream>>>(ei, flag);
    count_deg_k<<<(E + 255) / 256, 256, 0, stream>>>(ei, E, flag, cnt);
    dis_k<<<(n + 255) / 256, 256, 0, stream>>>(cnt, dis, n);
    scan_k<<<1, 1024, 0, stream>>>(cnt, offs, n);
    fill_csr_k<<<(E + 255) / 256, 256, 0, stream>>>(ei, E, flag, offs, cursor, dis, csrs, csrw);
    prep_w1_k<<<(K * 64 + 255) / 256, 256, 0, stream>>>(W1, Btw, K);

    dim3 g1(n / 128, 4);
    gemm1_mfma_k<<<g1, 256, 0, stream>>>(x, Btw, P, n, K, K / 4);
    size_t q = (size_t)n * 64 / 4;
    reduce4_k<<<(int)((q + 255) / 256), 256, 0, stream>>>((float4*)P, q);

    prop_k<64, true><<<(n * 64 + 255) / 256, 256, 0, stream>>>(P, offs, csrs, csrw, dis, b1, H1, n);
    gemm_small_k<64, 32><<<(n * 32 + 255) / 256, 256, 0, stream>>>(H1, W2, H2a, n);
    prop_k<32, true><<<(n * 32 + 255) / 256, 256, 0, stream>>>(H2a, offs, csrs, csrw, dis, b2, H2, n);
    gemm_small_k<32, 16><<<(n * 16 + 255) / 256, 256, 0, stream>>>(H2, W3, H3a, n);
    prop_softmax_k<<<(n * 16 + 255) / 256, 256, 0, stream>>>(H3a, offs, csrs, csrw, dis, b3, out, n);
}